// Round 3
// baseline (217.989 us; speedup 1.0000x reference)
//
#include <hip/hip_runtime.h>

// ScalarDistanceDeepSet: B=32, N=256, pairs P=32640 (upper tri, k=1)
// phi: s -> relu(s*W1+b1)[64] -> relu(.@W2+b2)[128], masked sum over pairs
// rho: pooled[128] -> 256 -> 128 -> 64
//
// g_e(s) is piecewise-linear in s with 64 shared breakpoints. Tables
// alpha/beta[seg][e] make per-(pair,channel) work 1 FMA + 1 max. EXACT.
//
// R9: R8's regression was a regalloc cliff: __launch_bounds__(512,8) caps
// VGPRs at 64; the batched interior + held fA/fB + fused rho tail pushed
// demand over the cap and the backend collapsed to VGPR_Count=16 with
// scratch spills in the inner loop (VALUBusy 8% at 48% occupancy, no
// FETCH/WRITE spike -> L2-resident scratch). Occupancy is LDS-capped at
// 4 blocks/CU (35.8KB) anyway, so the reg cap was pure downside. Only
// change: (512,8) -> (512,4). Keeps split halves, 33.3KB half-table,
// two-stage batched interior (4 ds_read_b64 in flight), fused rho.

#define NB 32
#define NN 256
#define PHI2 128
#define SEGS 65

// ---------------- Kernel A: build tables (+ zero pooled & counters) -------
// grid: 65 blocks (one per segment), 128 threads (one per output channel e)
// table2[h][seg][l] = {alpha, beta} for channel h*64+l
__global__ __launch_bounds__(128) void build_tables(
    const float* __restrict__ W1, const float* __restrict__ b1,
    const float* __restrict__ W2, const float* __restrict__ b2,
    float2* __restrict__ table2,   // [2][SEGS][64]
    float* __restrict__ tsort, float* __restrict__ pooled,
    int* __restrict__ cnt) {
  __shared__ float w2_s[64 * PHI2];   // 32 KB
  __shared__ float t_s[64], w1_s[64], b1_s[64];
  __shared__ int cat_s[64], rank_s[64];
  const int tid = threadIdx.x;
  const int seg = blockIdx.x;
  const float4* W2v = (const float4*)W2;
  float4* w2v = (float4*)w2_s;
  for (int i = tid; i < 64 * PHI2 / 4; i += 128) w2v[i] = W2v[i];
  if (tid < 64) {
    float w = W1[tid], bb = b1[tid];
    w1_s[tid] = w; b1_s[tid] = bb;
    int cat; float t;
    if (w > 0.f)      { cat = 0; t = -bb / w; }   // active for s > t
    else if (w < 0.f) { cat = 1; t = -bb / w; }   // active for s < t
    else              { cat = (bb > 0.f) ? 2 : 3; t = 0.f; } // always/never
    t_s[tid] = t; cat_s[tid] = cat;
  }
  __syncthreads();
  if (tid < 64) {
    float t = t_s[tid]; int r = 0;
    for (int k = 0; k < 64; ++k) {
      float tk = t_s[k];
      r += (tk < t) || (tk == t && k < tid);   // stable rank
    }
    rank_s[tid] = r;
    if (seg == 0) tsort[r] = t;
  }
  __syncthreads();
  // channel e = tid. seg(s) = #breakpoints strictly < s.
  float a = 0.f, bsum = b2[tid];
#pragma unroll 8
  for (int j = 0; j < 64; ++j) {
    int cat = cat_s[j], r = rank_s[j];
    bool act = (cat == 0) ? (seg > r) : (cat == 1) ? (seg <= r) : (cat == 2);
    float w2 = w2_s[j * PHI2 + tid];
    float m = act ? 1.f : 0.f;
    a    = fmaf(m * w1_s[j], w2, a);
    bsum = fmaf(m * b1_s[j], w2, bsum);
  }
  const int h = tid >> 6, l = tid & 63;
  table2[((h * SEGS) + seg) * 64 + l] = make_float2(a, bsum);
  if (seg == 0) {
    for (int i = tid; i < NB * PHI2; i += 128) pooled[i] = 0.f;
    if (tid < NB) cnt[tid] = 0;
  }
}

__device__ __forceinline__ float bcast(float v, int L) {
  return __int_as_float(__builtin_amdgcn_readlane(__float_as_int(v), L));
}
__device__ __forceinline__ int segof(float tv, float s) {
  return (int)__popcll(__ballot(tv < s));
}

// Single (pair, half-channel) visit: broadcast s from lane L (uniform),
// segment via ballot over register-held breakpoints, one ds_read_b64.
__device__ __forceinline__ void visit(float comp, int L, float tv, int lane,
                                      const float2* ab_s, float& acc) {
  float s = bcast(comp, L);
  float2 p = ab_s[segof(tv, s) * 64 + lane];
  acc += fmaxf(fmaf(p.x, s, p.y), 0.f);
}

// Dynamic-component visit for ragged row edges (<=6 per row).
__device__ __forceinline__ void visit_dyn(const float4& f4, int j, float tv,
                                          int lane, const float2* ab_s,
                                          float& acc) {
  int c = j & 3;
  float comp = (c == 0) ? f4.x : (c == 1) ? f4.y : (c == 2) ? f4.z : f4.w;
  visit(comp, j >> 2, tv, lane, ab_s, acc);
}

// Process one row: f4 holds the full 256-float row across the wave
// (lane holds cols 4*lane..4*lane+3). Valid cols j in [i0+1, len-1].
// Interior groups are batched two-stage: addresses+loads first, FMAs after,
// so 4 ds_read_b64 are in flight per group (accum order unchanged -> exact).
__device__ __forceinline__ void do_row(const float4& f4, int i0, int len,
                                       float tv, int lane,
                                       const float2* ab_s, float& acc) {
  const int jlo = i0 + 1, jhi = len - 1;   // inclusive; jhi >= jlo guaranteed
  const int fullLo = (jlo + 3) >> 2;       // first fully-valid 4-group
  const int fullHi = (jhi >= 3) ? ((jhi - 3) >> 2) : -1;  // last fully-valid
  if (fullLo > fullHi) {
    for (int j = jlo; j <= jhi; ++j) visit_dyn(f4, j, tv, lane, ab_s, acc);
    return;
  }
  // low ragged edge
  for (int j = jlo; j < fullLo * 4; ++j) visit_dyn(f4, j, tv, lane, ab_s, acc);
  // interior full groups: uniform L in SGPR, static components, batched
#pragma unroll 2
  for (int L = fullLo; L <= fullHi; ++L) {
    float s0 = bcast(f4.x, L), s1 = bcast(f4.y, L);
    float s2 = bcast(f4.z, L), s3 = bcast(f4.w, L);
    int p0 = segof(tv, s0), p1 = segof(tv, s1);
    int p2 = segof(tv, s2), p3 = segof(tv, s3);
    float2 q0 = ab_s[p0 * 64 + lane];
    float2 q1 = ab_s[p1 * 64 + lane];
    float2 q2 = ab_s[p2 * 64 + lane];
    float2 q3 = ab_s[p3 * 64 + lane];
    acc += fmaxf(fmaf(q0.x, s0, q0.y), 0.f);
    acc += fmaxf(fmaf(q1.x, s1, q1.y), 0.f);
    acc += fmaxf(fmaf(q2.x, s2, q2.y), 0.f);
    acc += fmaxf(fmaf(q3.x, s3, q3.y), 0.f);
  }
  // high ragged edge
  for (int j = fullHi * 4 + 4; j <= jhi; ++j)
    visit_dyn(f4, j, tv, lane, ab_s, acc);
}

// ---------------- Kernel B: phi + masked pooling + fused rho --------------
// grid: (16 row-chunks, 2 halves, 32 batches) x 512 threads (8 waves).
// Wave w owns row r = chunk*8+w (0..127) and its mirror 254-r (balanced).
// Last participating block of batch b (per-batch device counter over BOTH
// halves) runs the rho MLP for that batch.
// (512,4): occupancy is LDS-capped at 4 blocks/CU; a (512,8) VGPR cap of 64
// caused spill-collapse (R8: VGPR_Count=16). 128-reg budget, ~52 expected.
__global__ __launch_bounds__(512, 4) void phi_pool_rho(
    const float* __restrict__ dm, const int* __restrict__ lengths,
    const float2* __restrict__ table2, const float* __restrict__ tsort,
    float* __restrict__ pooled, int* __restrict__ cnt,
    const float* __restrict__ W3, const float* __restrict__ b3,
    const float* __restrict__ W4, const float* __restrict__ b4,
    const float* __restrict__ W5, const float* __restrict__ b5,
    float* __restrict__ out) {
  __shared__ float2 ab_s[SEGS * 64];   // 33,280 B -> 4 blocks/CU
  __shared__ float p_s[128], r1_s[256], r2_s[128];
  __shared__ int lastflag;
  const int chunk = blockIdx.x;   // 0..15
  const int h     = blockIdx.y;   // channel half
  const int b     = blockIdx.z;   // batch
  const int tid = threadIdx.x;
  const int lane = tid & 63, w = tid >> 6;

  const int len = lengths[b];
  // block-uniform early exit: no primary row (8c) and no mirror row (247-8c)
  if (8 * chunk > len - 2 && 247 - 8 * chunk > len - 2) return;

  const float2* tg = table2 + h * SEGS * 64;
  for (int i = tid; i < SEGS * 64; i += 512) ab_s[i] = tg[i];
  __syncthreads();

  const float tv = tsort[lane];      // breakpoint in register, one per lane
  const float* dmb = dm + (size_t)b * (NN * NN);
  float acc = 0.f;

  const int rA = chunk * 8 + w;      // 0..127
  const int rB = 254 - rA;           // 127..254
  // issue both full-row loads up-front (always address-valid)
  const float4 fA = ((const float4*)(dmb + rA * NN))[lane];
  const float4 fB = ((const float4*)(dmb + rB * NN))[lane];
  if (rA <= len - 2) do_row(fA, rA, len, tv, lane, ab_s, acc);
  if (rB != rA && rB <= len - 2) do_row(fB, rB, len, tv, lane, ab_s, acc);

  atomicAdd(&pooled[b * PHI2 + h * 64 + lane], acc);

  // release: per-thread fence, then barrier (all block atomics reach the
  // device coherence point before the counter signal).
  __threadfence();
  __syncthreads();
  if (tid == 0) {
    int npart = 0;
    for (int c = 0; c < 16; ++c)
      npart += (8 * c <= len - 2) || (247 - 8 * c <= len - 2);
    npart *= 2;   // both channel halves
    lastflag = (atomicAdd(&cnt[b], 1) == npart - 1) ? 1 : 0;
  }
  __syncthreads();
  if (!lastflag) return;

  // ---- rho for batch b (runs once, in the last-arriving block) ----
  // acquire-read pooled via atomic RMW (same coherence point as writers).
  if (tid < 128) p_s[tid] = atomicAdd(&pooled[b * PHI2 + tid], 0.0f);
  __syncthreads();
  if (tid < 256) {
    float acc2 = b3[tid];
#pragma unroll 8
    for (int k = 0; k < 128; ++k) acc2 = fmaf(p_s[k], W3[k * 256 + tid], acc2);
    r1_s[tid] = fmaxf(acc2, 0.f);
  }
  __syncthreads();
  if (tid < 128) {
    float acc2 = b4[tid];
#pragma unroll 8
    for (int k = 0; k < 256; ++k) acc2 = fmaf(r1_s[k], W4[k * 128 + tid], acc2);
    r2_s[tid] = fmaxf(acc2, 0.f);
  }
  __syncthreads();
  if (tid < 64) {
    float acc2 = b5[tid];
#pragma unroll 8
    for (int k = 0; k < 128; ++k) acc2 = fmaf(r2_s[k], W5[k * 64 + tid], acc2);
    out[b * 64 + tid] = acc2;
  }
}

extern "C" void kernel_launch(void* const* d_in, const int* in_sizes, int n_in,
                              void* d_out, int out_size, void* d_ws, size_t ws_size,
                              hipStream_t stream) {
  const float* dm      = (const float*)d_in[0];
  const int*   lengths = (const int*)d_in[1];
  const float* W1 = (const float*)d_in[2];
  const float* b1 = (const float*)d_in[3];
  const float* W2 = (const float*)d_in[4];
  const float* b2 = (const float*)d_in[5];
  const float* W3 = (const float*)d_in[6];
  const float* b3 = (const float*)d_in[7];
  const float* W4 = (const float*)d_in[8];
  const float* b4 = (const float*)d_in[9];
  const float* W5 = (const float*)d_in[10];
  const float* b5 = (const float*)d_in[11];

  float* ws = (float*)d_ws;
  float2* table2 = (float2*)ws;          // 2*65*64 float2 = 16640 floats
  float* tsort   = ws + 16640;           // 64
  float* pooled  = ws + 16704;           // 32*128 = 4096
  int*   cnt     = (int*)(ws + 20800);   // 32

  build_tables<<<SEGS, 128, 0, stream>>>(W1, b1, W2, b2, table2, tsort,
                                         pooled, cnt);
  phi_pool_rho<<<dim3(16, 2, NB), 512, 0, stream>>>(
      dm, lengths, table2, tsort, pooled, cnt,
      W3, b3, W4, b4, W5, b5, (float*)d_out);
}

// Round 4
// 161.845 us; speedup vs baseline: 1.3469x; 1.3469x over previous
//
#include <hip/hip_runtime.h>

// ScalarDistanceDeepSet: B=32, N=256, pairs P=32640 (upper tri, k=1)
// phi: s -> relu(s*W1+b1)[64] -> relu(.@W2+b2)[128], masked sum over pairs
// rho: pooled[128] -> 256 -> 128 -> 64
//
// g_e(s) is piecewise-linear in s with 64 shared breakpoints. Tables
// alpha/beta[seg][e] make per-(pair,channel) work 1 FMA + 1 max. EXACT.
//
// R10: R8/R9's two-stage batched interior + fused rho tail made the
// backend collapse to VGPR_Count=16 (spill code in the hot loop) under
// BOTH (512,8) and (512,4) -> that source pattern is abandoned. This
// round restores the R6 kernel structure verbatim (3 kernels, visit-by-
// visit interior, (512,8)) and makes ONE change: column-group PARITY
// split. Grid y = half*4 + par (16,8,32 = 4096 blocks); block par takes
// interior 4-col groups L with L%4==par (ragged edges on par==0). Any
// row's serial visit chain shrinks ~4x regardless of len (the mirror-row
// pairing only balanced len~255), and 16 queued blocks/CU keep residency
// at the 4-block LDS cap instead of draining when early-exit blocks
// finish (R6: exactly 4 blocks/CU queued -> CU starvation in the tail).

#define NB 32
#define NN 256
#define PHI2 128
#define SEGS 65

// ---------------- Kernel A: build tables ----------------
// grid: 65 blocks (one per segment), 128 threads (one per output channel e)
// table2[h][seg][l] = {alpha, beta} for channel h*64+l
__global__ __launch_bounds__(128) void build_tables(
    const float* __restrict__ W1, const float* __restrict__ b1,
    const float* __restrict__ W2, const float* __restrict__ b2,
    float2* __restrict__ table2,   // [2][SEGS][64]
    float* __restrict__ tsort, float* __restrict__ pooled) {
  __shared__ float w2_s[64 * PHI2];   // 32 KB
  __shared__ float t_s[64], w1_s[64], b1_s[64];
  __shared__ int cat_s[64], rank_s[64];
  const int tid = threadIdx.x;
  const int seg = blockIdx.x;
  const float4* W2v = (const float4*)W2;
  float4* w2v = (float4*)w2_s;
  for (int i = tid; i < 64 * PHI2 / 4; i += 128) w2v[i] = W2v[i];
  if (tid < 64) {
    float w = W1[tid], bb = b1[tid];
    w1_s[tid] = w; b1_s[tid] = bb;
    int cat; float t;
    if (w > 0.f)      { cat = 0; t = -bb / w; }   // active for s > t
    else if (w < 0.f) { cat = 1; t = -bb / w; }   // active for s < t
    else              { cat = (bb > 0.f) ? 2 : 3; t = 0.f; } // always/never
    t_s[tid] = t; cat_s[tid] = cat;
  }
  __syncthreads();
  if (tid < 64) {
    float t = t_s[tid]; int r = 0;
    for (int k = 0; k < 64; ++k) {
      float tk = t_s[k];
      r += (tk < t) || (tk == t && k < tid);   // stable rank
    }
    rank_s[tid] = r;
    if (seg == 0) tsort[r] = t;
  }
  __syncthreads();
  // channel e = tid. seg(s) = #breakpoints strictly < s.
  float a = 0.f, bsum = b2[tid];
#pragma unroll 8
  for (int j = 0; j < 64; ++j) {
    int cat = cat_s[j], r = rank_s[j];
    bool act = (cat == 0) ? (seg > r) : (cat == 1) ? (seg <= r) : (cat == 2);
    float w2 = w2_s[j * PHI2 + tid];
    float m = act ? 1.f : 0.f;
    a    = fmaf(m * w1_s[j], w2, a);
    bsum = fmaf(m * b1_s[j], w2, bsum);
  }
  const int h = tid >> 6, l = tid & 63;
  table2[((h * SEGS) + seg) * 64 + l] = make_float2(a, bsum);
  if (seg == 0) {
    for (int i = tid; i < NB * PHI2; i += 128) pooled[i] = 0.f;
  }
}

// One (pair, channel) visit: broadcast s from lane L (uniform), segment via
// ballot over register-held sorted breakpoints, one contiguous ds_read_b64.
__device__ __forceinline__ void visit(float comp, int L, float tv, int lane,
                                      const float2* ab_s, float& acc) {
  float s = __int_as_float(__builtin_amdgcn_readlane(__float_as_int(comp), L));
  int pos = (int)__popcll(__ballot(tv < s));
  float2 p = ab_s[pos * 64 + lane];
  acc += fmaxf(fmaf(p.x, s, p.y), 0.f);
}

// Dynamic-component visit for ragged row edges (<=6 per row).
__device__ __forceinline__ void visit_dyn(const float4& f4, int j, float tv,
                                          int lane, const float2* ab_s,
                                          float& acc) {
  int c = j & 3;
  float comp = (c == 0) ? f4.x : (c == 1) ? f4.y : (c == 2) ? f4.z : f4.w;
  visit(comp, j >> 2, tv, lane, ab_s, acc);
}

// Process one row: f4 holds the full 256-float row across the wave
// (lane holds cols 4*lane..4*lane+3). Valid cols j in [i0+1, len-1].
// This block only handles interior 4-groups L with (L & 3) == par;
// ragged edges are handled by par==0.
__device__ __forceinline__ void do_row(const float4& f4, int i0, int len,
                                       float tv, int lane, int par,
                                       const float2* ab_s, float& acc) {
  const int jlo = i0 + 1, jhi = len - 1;   // inclusive; jhi >= jlo guaranteed
  const int fullLo = (jlo + 3) >> 2;       // first fully-valid 4-group
  const int fullHi = (jhi >= 3) ? ((jhi - 3) >> 2) : -1;  // last fully-valid
  if (fullLo > fullHi) {
    if (par == 0)
      for (int j = jlo; j <= jhi; ++j) visit_dyn(f4, j, tv, lane, ab_s, acc);
    return;
  }
  if (par == 0) {
    // low ragged edge
    for (int j = jlo; j < fullLo * 4; ++j)
      visit_dyn(f4, j, tv, lane, ab_s, acc);
    // high ragged edge
    for (int j = fullHi * 4 + 4; j <= jhi; ++j)
      visit_dyn(f4, j, tv, lane, ab_s, acc);
  }
  // interior full groups of this parity: uniform L in SGPR, static comps
  const int Lstart = fullLo + ((par - fullLo) & 3);
#pragma unroll 2
  for (int L = Lstart; L <= fullHi; L += 4) {
    visit(f4.x, L, tv, lane, ab_s, acc);
    visit(f4.y, L, tv, lane, ab_s, acc);
    visit(f4.z, L, tv, lane, ab_s, acc);
    visit(f4.w, L, tv, lane, ab_s, acc);
  }
}

// ---------------- Kernel B: phi + masked pooling ----------------
// grid: (16 row-chunks, 2 halves x 4 parities, 32 batches) x 512 threads.
// Wave w owns row r = chunk*8+w (0..127) and its mirror 254-r.
__global__ __launch_bounds__(512, 8) void phi_pool(
    const float* __restrict__ dm, const int* __restrict__ lengths,
    const float2* __restrict__ table2, const float* __restrict__ tsort,
    float* __restrict__ pooled) {
  __shared__ float2 ab_s[SEGS * 64];   // 33,280 B -> 4 blocks/CU
  const int chunk = blockIdx.x;        // 0..15
  const int h     = blockIdx.y >> 2;   // channel half
  const int par   = blockIdx.y & 3;    // column-group parity
  const int b     = blockIdx.z;        // batch
  const int tid = threadIdx.x;
  const int lane = tid & 63, w = tid >> 6;

  const int len = lengths[b];
  // block-uniform early exit: no primary row (8c) and no mirror row (247-8c)
  if (8 * chunk > len - 2 && 247 - 8 * chunk > len - 2) return;

  const float2* tg = table2 + h * SEGS * 64;
  for (int i = tid; i < SEGS * 64; i += 512) ab_s[i] = tg[i];
  __syncthreads();

  const float tv = tsort[lane];      // breakpoint in register, one per lane
  const float* dmb = dm + (size_t)b * (NN * NN);
  float acc = 0.f;

  const int rA = chunk * 8 + w;      // 0..127
  const int rB = 254 - rA;           // 127..254
  // issue both full-row loads up-front (always address-valid)
  const float4 fA = ((const float4*)(dmb + rA * NN))[lane];
  const float4 fB = ((const float4*)(dmb + rB * NN))[lane];
  if (rA <= len - 2) do_row(fA, rA, len, tv, lane, par, ab_s, acc);
  if (rB != rA && rB <= len - 2) do_row(fB, rB, len, tv, lane, par, ab_s, acc);

  atomicAdd(&pooled[b * PHI2 + h * 64 + lane], acc);
}

// ---------------- Kernel C: rho MLP ----------------
// grid: 32 blocks (one per batch), 256 threads. Weight layers staged
// through one reused 128 KB LDS buffer with independent float4 loads.
__global__ __launch_bounds__(256) void rho_mlp(
    const float* __restrict__ pooled,
    const float* __restrict__ W3, const float* __restrict__ b3,
    const float* __restrict__ W4, const float* __restrict__ b4,
    const float* __restrict__ W5, const float* __restrict__ b5,
    float* __restrict__ out) {
  __shared__ float w_s[128 * 256];     // 128 KB, reused per layer
  __shared__ float p_s[128], r1_s[256], r2_s[128];
  const int b = blockIdx.x, tid = threadIdx.x;
  float4* wsv = (float4*)w_s;
  {
    const float4* w3v = (const float4*)W3;
    for (int i = tid; i < 8192; i += 256) wsv[i] = w3v[i];
  }
  if (tid < 128) p_s[tid] = pooled[b * 128 + tid];
  __syncthreads();
  {
    float acc = b3[tid];
#pragma unroll 8
    for (int k = 0; k < 128; ++k) acc = fmaf(p_s[k], w_s[k * 256 + tid], acc);
    r1_s[tid] = fmaxf(acc, 0.f);
  }
  __syncthreads();
  {
    const float4* w4v = (const float4*)W4;
    for (int i = tid; i < 8192; i += 256) wsv[i] = w4v[i];
  }
  __syncthreads();
  if (tid < 128) {
    float acc = b4[tid];
#pragma unroll 8
    for (int k = 0; k < 256; ++k) acc = fmaf(r1_s[k], w_s[k * 128 + tid], acc);
    r2_s[tid] = fmaxf(acc, 0.f);
  }
  __syncthreads();
  {
    const float4* w5v = (const float4*)W5;
    for (int i = tid; i < 2048; i += 256) wsv[i] = w5v[i];
  }
  __syncthreads();
  if (tid < 64) {
    float acc = b5[tid];
#pragma unroll 8
    for (int k = 0; k < 128; ++k) acc = fmaf(r2_s[k], w_s[k * 64 + tid], acc);
    out[b * 64 + tid] = acc;
  }
}

extern "C" void kernel_launch(void* const* d_in, const int* in_sizes, int n_in,
                              void* d_out, int out_size, void* d_ws, size_t ws_size,
                              hipStream_t stream) {
  const float* dm      = (const float*)d_in[0];
  const int*   lengths = (const int*)d_in[1];
  const float* W1 = (const float*)d_in[2];
  const float* b1 = (const float*)d_in[3];
  const float* W2 = (const float*)d_in[4];
  const float* b2 = (const float*)d_in[5];
  const float* W3 = (const float*)d_in[6];
  const float* b3 = (const float*)d_in[7];
  const float* W4 = (const float*)d_in[8];
  const float* b4 = (const float*)d_in[9];
  const float* W5 = (const float*)d_in[10];
  const float* b5 = (const float*)d_in[11];

  float* ws = (float*)d_ws;
  float2* table2 = (float2*)ws;          // 2*65*64 float2 = 16640 floats
  float* tsort   = ws + 16640;           // 64
  float* pooled  = ws + 16704;           // 32*128 = 4096

  build_tables<<<SEGS, 128, 0, stream>>>(W1, b1, W2, b2, table2, tsort, pooled);
  phi_pool<<<dim3(16, 8, NB), 512, 0, stream>>>(dm, lengths, table2, tsort, pooled);
  rho_mlp<<<NB, 256, 0, stream>>>(pooled, W3, b3, W4, b4, W5, b5, (float*)d_out);
}